// Round 3
// baseline (225.263 us; speedup 1.0000x reference)
//
#include <hip/hip_runtime.h>

#define N_NODES 50000
#define N_EDGES 800000
#define DIM 96
#define FEAT_ELEMS (N_NODES * DIM)
#define NBLK 196    // ceil(50000/256)
#define CNT_STRIDE 16            // one counter per 64B line (anti line-lock)
#define CNT_INTS (N_NODES * CNT_STRIDE)   // 800000 ints = 3.2 MB
#define ZBLK 196    // ceil(CNT_INTS/16 int4s / 256) = ceil(50000/256)... see prolog
#define ZBLK4 782   // ceil(200000 int4 stores / 256)
#define EGRID 3125  // 800000/256
#define CGRID 4688  // ceil(FEAT_ELEMS/4/256)
#define WGRID 10    // 2 weight matrices x 5 blocks (1152 frags each)
#define AGRID 12500 // 50000 waves (1 node/wave) * 64 / 256
#define GGRID 782   // ceil(50000/64)

typedef __attribute__((ext_vector_type(8))) short short8;   // 8 bf16 (4 VGPRs)
typedef __attribute__((ext_vector_type(4))) float float4v;  // 4 fp32 acc

// ---------------------------------------------------------------------------
// bf16 helpers via raw bit ops
// ---------------------------------------------------------------------------
__device__ __forceinline__ float bf16_to_f32(unsigned short u) {
    unsigned int w = ((unsigned int)u) << 16;
    float f;
    __builtin_memcpy(&f, &w, 4);
    return f;
}
__device__ __forceinline__ unsigned short f32_to_bf16_rne(float f) {
    unsigned int w;
    __builtin_memcpy(&w, &f, 4);
    unsigned int r = (w + 0x7FFFu + ((w >> 16) & 1u)) >> 16;
    return (unsigned short)r;
}
__device__ __forceinline__ unsigned int pack_bf16x2(float lo, float hi) {
    return (unsigned int)f32_to_bf16_rne(lo) | ((unsigned int)f32_to_bf16_rne(hi) << 16);
}

__device__ __forceinline__ int edge_at(const void* ep, int is64, int idx) {
    if (is64) return (int)((const long long*)ep)[idx];
    return ((const int*)ep)[idx];
}

// ---------------------------------------------------------------------------
// prolog: blocks [0,ZBLK4) zero the padded cnt array (int4 stores); block
// ZBLK4 detects edge dtype (int64 => odd 32-bit words all zero => flagE=1);
// block ZBLK4+1 detects float dtype of x (bf16 => exponent test => flagF=1).
// ---------------------------------------------------------------------------
__global__ __launch_bounds__(256) void prolog_kernel(const unsigned int* edges,
                                                     const unsigned int* x,
                                                     int* flagE, int* flagF, int* cnt) {
    __shared__ unsigned int sh[256];
    int t = threadIdx.x;
    int b = blockIdx.x;
    if (b < ZBLK4) {
        int i4 = b * 256 + t;
        if (i4 < CNT_INTS / 4) ((int4*)cnt)[i4] = make_int4(0, 0, 0, 0);
        return;
    }
    if (b == ZBLK4) {
        if (t < 64) {
            unsigned int acc = 0;
            for (int k = 0; k < 4; ++k) {
                int idx = t * 4 + k;           // 0..255
                int pos = 1 + 2 * idx * 3109;  // odd words, max 1,585,591 < 1.6M
                acc |= edges[pos];
            }
            sh[t] = acc;
        }
        __syncthreads();
        if (t == 0) {
            unsigned int a = 0;
            for (int i = 0; i < 64; ++i) a |= sh[i];
            *flagE = (a == 0u) ? 1 : 0;
        }
        return;
    }
    // b == ZBLK4+1: feature dtype
    unsigned int w = x[t * 9000];  // max 2,295,000 < 2.4M words (bf16 interp)
    unsigned int e = (w >> 7) & 0xFFu;
    sh[t] = (e >= 100u && e <= 135u) ? 1u : 0u;
    __syncthreads();
    if (t == 0) {
        int c = 0;
        for (int i = 0; i < 256; ++i) c += (int)sh[i];
        *flagF = (c >= 128) ? 1 : 0;
    }
}

// ---------------------------------------------------------------------------
// fused prep: blocks [0,EGRID) count+compact+rank (counters padded to one
// per 64B cacheline so L2 atomics to different nodes never share a line);
// [EGRID,EGRID+CGRID) convert x -> bf16; [EGRID+CGRID, +WGRID) build
// B-fragment-swizzled copies of W1/W2 in global memory. Frag
// f=(kt*6+nt)*64+lane holds W[kt*32+(lane>>4)*8+j][nt*16+(lane&15)], j=0..7.
// ---------------------------------------------------------------------------
__global__ __launch_bounds__(256) void count_convert_kernel(const void* __restrict__ edges,
                                                            const void* __restrict__ x,
                                                            const void* __restrict__ W1,
                                                            const void* __restrict__ W2,
                                                            const int* __restrict__ flagE,
                                                            const int* __restrict__ flagF,
                                                            int* __restrict__ cnt,
                                                            unsigned short* __restrict__ srcu,
                                                            unsigned short* __restrict__ dstu,
                                                            unsigned short* __restrict__ rank,
                                                            unsigned short* __restrict__ xb,
                                                            unsigned short* __restrict__ wsw1,
                                                            unsigned short* __restrict__ wsw2) {
    int b = blockIdx.x;
    if (b < EGRID) {
        int e = b * 256 + threadIdx.x;  // EGRID*256 == N_EDGES exactly
        int is64 = *flagE;
        int s = edge_at(edges, is64, e);
        int d = edge_at(edges, is64, N_EDGES + e);
        srcu[e] = (unsigned short)s;
        dstu[e] = (unsigned short)d;
        rank[e] = (unsigned short)atomicAdd(&cnt[d * CNT_STRIDE], 1);
        return;
    }
    if (b < EGRID + CGRID) {
        int i4 = ((b - EGRID) * 256 + threadIdx.x) * 4;
        if (i4 >= FEAT_ELEMS) return;
        int isbf16 = *flagF;
        ushort4 o;
        if (isbf16) {
            o = *(const ushort4*)((const unsigned short*)x + i4);
        } else {
            float4 v = *(const float4*)((const float*)x + i4);
            o.x = f32_to_bf16_rne(v.x);
            o.y = f32_to_bf16_rne(v.y);
            o.z = f32_to_bf16_rne(v.z);
            o.w = f32_to_bf16_rne(v.w);
        }
        *(ushort4*)(xb + i4) = o;
        return;
    }
    // weight swizzle build
    int wi = b - EGRID - CGRID;          // 0..9
    int which = wi / 5;                  // 0 -> W1, 1 -> W2
    int f = (wi - which * 5) * 256 + threadIdx.x;
    if (f >= 1152) return;
    const void* Wp = which ? W2 : W1;
    unsigned short* Op = which ? wsw2 : wsw1;
    int wBf16 = *flagF;
    int kt = f / 384;
    int rem = f - kt * 384;
    int nt = rem >> 6;
    int ln64 = rem & 63;
    int q = ln64 >> 4, ln = ln64 & 15;
    int k0 = kt * 32 + q * 8;
    int n = nt * 16 + ln;
    unsigned short e[8];
    if (wBf16) {
        const unsigned short* Wh = (const unsigned short*)Wp;
        #pragma unroll
        for (int j = 0; j < 8; ++j) e[j] = Wh[(k0 + j) * DIM + n];
    } else {
        const float* Wf = (const float*)Wp;
        #pragma unroll
        for (int j = 0; j < 8; ++j) e[j] = f32_to_bf16_rne(Wf[(k0 + j) * DIM + n]);
    }
    uint4 pk;
    pk.x = (unsigned int)e[0] | ((unsigned int)e[1] << 16);
    pk.y = (unsigned int)e[2] | ((unsigned int)e[3] << 16);
    pk.z = (unsigned int)e[4] | ((unsigned int)e[5] << 16);
    pk.w = (unsigned int)e[6] | ((unsigned int)e[7] << 16);
    *(uint4*)&Op[f * 8] = pk;
}

// ---------------------------------------------------------------------------
// scan phase 1: per-block sums of cnt (strided reads of padded counters)
// ---------------------------------------------------------------------------
__global__ __launch_bounds__(256) void scan_blocksum_kernel(const int* cnt, int* blockSums) {
    __shared__ int sh[256];
    int i = blockIdx.x * 256 + threadIdx.x;
    sh[threadIdx.x] = (i < N_NODES) ? cnt[i * CNT_STRIDE] : 0;
    __syncthreads();
    for (int off = 128; off > 0; off >>= 1) {
        if (threadIdx.x < off) sh[threadIdx.x] += sh[threadIdx.x + off];
        __syncthreads();
    }
    if (threadIdx.x == 0) blockSums[blockIdx.x] = sh[0];
}

// ---------------------------------------------------------------------------
// scan phase 2 (merged offsets+apply): every block redundantly scans the 196
// block sums in LDS, derives its own exclusive offset, then scans its 256
// cnt entries -> row_ptr (+ dinv). Block 0 thread 0 writes the total.
// ---------------------------------------------------------------------------
__global__ __launch_bounds__(256) void scan_apply_kernel(const int* __restrict__ cnt,
                                                         const int* __restrict__ blockSums,
                                                         int* __restrict__ row_ptr,
                                                         float* __restrict__ dinv) {
    __shared__ int sb[256];
    __shared__ int sh[256];
    int t = threadIdx.x;
    sb[t] = (t < NBLK) ? blockSums[t] : 0;
    __syncthreads();
    for (int off = 1; off < 256; off <<= 1) {
        int u = (t >= off) ? sb[t - off] : 0;
        __syncthreads();
        sb[t] += u;
        __syncthreads();
    }
    int b = blockIdx.x;
    int blockOff = (b == 0) ? 0 : sb[b - 1];  // exclusive prefix of this block
    if (b == 0 && t == 0) row_ptr[N_NODES] = sb[NBLK - 1];

    int i = b * 256 + t;
    int c = (i < N_NODES) ? cnt[i * CNT_STRIDE] : 0;
    sh[t] = c;
    __syncthreads();
    for (int off = 1; off < 256; off <<= 1) {
        int u = (t >= off) ? sh[t - off] : 0;
        __syncthreads();
        sh[t] += u;
        __syncthreads();
    }
    if (i < N_NODES) {
        row_ptr[i] = sh[t] - c + blockOff;
        dinv[i]    = rsqrtf((float)(c + 1));  // +1 self-loop
    }
}

// ---------------------------------------------------------------------------
// fill (rank-based direct scatter, NO atomics). Also precomputes per-edge
// weight dinv[s]*dinv[d] in fp32 so the gather's dependent chain is depth 2.
// ---------------------------------------------------------------------------
__global__ __launch_bounds__(256) void fill_direct_kernel(const unsigned short* __restrict__ dstu,
                                                          const unsigned short* __restrict__ srcu,
                                                          const unsigned short* __restrict__ rank,
                                                          const int* __restrict__ row_ptr,
                                                          const float* __restrict__ dinv,
                                                          unsigned short* __restrict__ csr_src,
                                                          float* __restrict__ csr_w) {
    int e = blockIdx.x * 256 + threadIdx.x;
    if (e >= N_EDGES) return;
    int d = dstu[e];
    int s = srcu[e];
    int pos = row_ptr[d] + (int)rank[e];
    csr_src[pos] = (unsigned short)s;
    csr_w[pos]   = dinv[s] * dinv[d];
}

// ---------------------------------------------------------------------------
// Gather-aggregate: ONE NODE PER WAVE. 64 lanes = 16 dim-lanes x 4 edge-ways.
// Way w handles edges e0+w, e0+w+4, ... (2-edge unroll -> 8 edges in flight
// per wave). No intra-wave degree divergence (all lanes share one edge list).
// Partial sums combine via __shfl_xor(16/32); way-0 lanes add the self term
// and store. 3.2M threads -> full latency hiding.
// ---------------------------------------------------------------------------
__global__ __launch_bounds__(256) void gather_kernel(const unsigned short* __restrict__ feat,
                                                     const int* __restrict__ row_ptr,
                                                     const unsigned short* __restrict__ csr_src,
                                                     const float* __restrict__ csr_w,
                                                     const float* __restrict__ dinv,
                                                     unsigned short* __restrict__ aggb) {
    int gid = blockIdx.x * 256 + threadIdx.x;
    int g = gid >> 6;      // AGRID*256/64 == N_NODES exactly
    int lane = gid & 63;
    int way = lane >> 4;
    int l = lane & 15;
    float a0 = 0.f, a1 = 0.f, a2 = 0.f, a3 = 0.f, a4 = 0.f, a5 = 0.f;
    int e0 = row_ptr[g], e1 = row_ptr[g + 1];
    int e = e0 + way;
    for (; e + 4 < e1; e += 8) {
        int s0 = csr_src[e];
        int s1 = csr_src[e + 4];
        float w0 = csr_w[e];
        float w1 = csr_w[e + 4];
        int b0 = s0 * DIM + l * 2;
        int b1 = s1 * DIM + l * 2;
        ushort2 p0 = *(const ushort2*)&feat[b0];
        ushort2 p1 = *(const ushort2*)&feat[b0 + 32];
        ushort2 p2 = *(const ushort2*)&feat[b0 + 64];
        ushort2 q0 = *(const ushort2*)&feat[b1];
        ushort2 q1 = *(const ushort2*)&feat[b1 + 32];
        ushort2 q2 = *(const ushort2*)&feat[b1 + 64];
        a0 = fmaf(w0, bf16_to_f32(p0.x), a0);  a1 = fmaf(w0, bf16_to_f32(p0.y), a1);
        a2 = fmaf(w0, bf16_to_f32(p1.x), a2);  a3 = fmaf(w0, bf16_to_f32(p1.y), a3);
        a4 = fmaf(w0, bf16_to_f32(p2.x), a4);  a5 = fmaf(w0, bf16_to_f32(p2.y), a5);
        a0 = fmaf(w1, bf16_to_f32(q0.x), a0);  a1 = fmaf(w1, bf16_to_f32(q0.y), a1);
        a2 = fmaf(w1, bf16_to_f32(q1.x), a2);  a3 = fmaf(w1, bf16_to_f32(q1.y), a3);
        a4 = fmaf(w1, bf16_to_f32(q2.x), a4);  a5 = fmaf(w1, bf16_to_f32(q2.y), a5);
    }
    if (e < e1) {
        int s = csr_src[e];
        float w = csr_w[e];
        int b0 = s * DIM + l * 2;
        ushort2 p0 = *(const ushort2*)&feat[b0];
        ushort2 p1 = *(const ushort2*)&feat[b0 + 32];
        ushort2 p2 = *(const ushort2*)&feat[b0 + 64];
        a0 = fmaf(w, bf16_to_f32(p0.x), a0);  a1 = fmaf(w, bf16_to_f32(p0.y), a1);
        a2 = fmaf(w, bf16_to_f32(p1.x), a2);  a3 = fmaf(w, bf16_to_f32(p1.y), a3);
        a4 = fmaf(w, bf16_to_f32(p2.x), a4);  a5 = fmaf(w, bf16_to_f32(p2.y), a5);
    }
    if (way == 0) {  // self-loop term
        float di = dinv[g];
        float ws = di * di;
        int gb = g * DIM + l * 2;
        ushort2 sv0 = *(const ushort2*)&feat[gb];
        ushort2 sv1 = *(const ushort2*)&feat[gb + 32];
        ushort2 sv2 = *(const ushort2*)&feat[gb + 64];
        a0 = fmaf(ws, bf16_to_f32(sv0.x), a0);  a1 = fmaf(ws, bf16_to_f32(sv0.y), a1);
        a2 = fmaf(ws, bf16_to_f32(sv1.x), a2);  a3 = fmaf(ws, bf16_to_f32(sv1.y), a3);
        a4 = fmaf(ws, bf16_to_f32(sv2.x), a4);  a5 = fmaf(ws, bf16_to_f32(sv2.y), a5);
    }
    // reduce the 4 ways (lanes l, l+16, l+32, l+48)
    a0 += __shfl_xor(a0, 16); a0 += __shfl_xor(a0, 32);
    a1 += __shfl_xor(a1, 16); a1 += __shfl_xor(a1, 32);
    a2 += __shfl_xor(a2, 16); a2 += __shfl_xor(a2, 32);
    a3 += __shfl_xor(a3, 16); a3 += __shfl_xor(a3, 32);
    a4 += __shfl_xor(a4, 16); a4 += __shfl_xor(a4, 32);
    a5 += __shfl_xor(a5, 16); a5 += __shfl_xor(a5, 32);
    if (way == 0) {
        int gb = g * DIM + l * 2;
        *(unsigned int*)&aggb[gb]      = pack_bf16x2(a0, a1);
        *(unsigned int*)&aggb[gb + 32] = pack_bf16x2(a2, a3);
        *(unsigned int*)&aggb[gb + 64] = pack_bf16x2(a4, a5);
    }
}

// ---------------------------------------------------------------------------
// MFMA GEMM + bias + ReLU, NO LDS / NO syncs: out[M,96] = relu(A @ W + b).
// A bf16 [N_NODES,96]; Wsw pre-swizzled B-fragment table in global (18 KB,
// L2-broadcast). mfma_f32_16x16x32_bf16, K=3x32. 256 thr = 4 waves x 16 rows.
// C/D: col=lane&15, row=(lane>>4)*4+reg. outMode: 0=fp32,1=bf16,2=follow flagF
// ---------------------------------------------------------------------------
__global__ __launch_bounds__(256) void gemm_mfma_kernel(const unsigned short* __restrict__ A,
                                                        const unsigned short* __restrict__ Wsw,
                                                        const void* __restrict__ bias,
                                                        const int* __restrict__ flagF,
                                                        void* __restrict__ out, int outMode) {
    int wBf16 = *flagF;
    int outBf16 = (outMode == 2) ? wBf16 : outMode;
    int t = threadIdx.x;
    int wave = t >> 6;
    int lane = t & 63;
    int quad = lane >> 4, ln = lane & 15;
    int m0 = blockIdx.x * 64 + wave * 16;
    int arow = m0 + ln;
    bool arowok = (arow < N_NODES);

    float4v acc[6];
    #pragma unroll
    for (int nt = 0; nt < 6; ++nt) acc[nt] = (float4v){0.f, 0.f, 0.f, 0.f};

    #pragma unroll
    for (int kt = 0; kt < 3; ++kt) {
        short8 af;
        if (arowok) {
            af = *(const short8*)&A[arow * DIM + kt * 32 + quad * 8];
        } else {
            af = (short8){0, 0, 0, 0, 0, 0, 0, 0};
        }
        #pragma unroll
        for (int nt = 0; nt < 6; ++nt) {
            short8 bf = *(const short8*)&Wsw[((kt * 6 + nt) * 64 + lane) * 8];
            acc[nt] = __builtin_amdgcn_mfma_f32_16x16x32_bf16(af, bf, acc[nt], 0, 0, 0);
        }
    }

    #pragma unroll
    for (int nt = 0; nt < 6; ++nt) {
        int n = nt * 16 + ln;
        float bv = wBf16 ? bf16_to_f32(((const unsigned short*)bias)[n])
                         : ((const float*)bias)[n];
        #pragma unroll
        for (int reg = 0; reg < 4; ++reg) {
            int row = m0 + quad * 4 + reg;
            if (row >= N_NODES) continue;
            float v = fmaxf(acc[nt][reg] + bv, 0.0f);
            if (outBf16) ((unsigned short*)out)[row * DIM + n] = f32_to_bf16_rne(v);
            else         ((float*)out)[row * DIM + n] = v;
        }
    }
}

// ---------------------------------------------------------------------------
extern "C" void kernel_launch(void* const* d_in, const int* in_sizes, int n_in,
                              void* d_out, int out_size, void* d_ws, size_t ws_size,
                              hipStream_t stream) {
    const void* x  = d_in[0];
    const void* ei = d_in[1];
    const void* W1 = d_in[2];
    const void* b1 = d_in[3];
    const void* W2 = d_in[4];
    const void* b2 = d_in[5];

    char* base = (char*)d_ws;
    size_t off = 0;
    auto carve = [&](size_t bytes) -> void* {
        void* p = base + off;
        off += (bytes + 255) & ~(size_t)255;
        return p;
    };
    int*            flagE     = (int*)carve(4);
    int*            flagF     = (int*)carve(4);
    int*            cnt       = (int*)carve((size_t)CNT_INTS * 4);  // 3.2 MB padded
    int*            row_ptr   = (int*)carve((size_t)(N_NODES + 1) * 4);
    float*          dinv      = (float*)carve((size_t)N_NODES * 4);
    int*            blockSums = (int*)carve((size_t)NBLK * 4);
    unsigned short* srcu      = (unsigned short*)carve((size_t)N_EDGES * 2);
    unsigned short* dstu      = (unsigned short*)carve((size_t)N_EDGES * 2);
    unsigned short* rank      = (unsigned short*)carve((size_t)N_EDGES * 2);
    unsigned short* csr_src   = (unsigned short*)carve((size_t)N_EDGES * 2);
    float*          csr_w     = (float*)carve((size_t)N_EDGES * 4);
    unsigned short* wsw1      = (unsigned short*)carve((size_t)1152 * 8 * 2);
    unsigned short* wsw2      = (unsigned short*)carve((size_t)1152 * 8 * 2);
    unsigned short* aggb      = (unsigned short*)carve((size_t)FEAT_ELEMS * 2);
    unsigned short* xb        = (unsigned short*)carve((size_t)FEAT_ELEMS * 2);
    unsigned short* h         = (unsigned short*)carve((size_t)FEAT_ELEMS * 2);

    prolog_kernel<<<ZBLK4 + 2, 256, 0, stream>>>((const unsigned int*)ei,
                                                 (const unsigned int*)x, flagE, flagF, cnt);
    count_convert_kernel<<<EGRID + CGRID + WGRID, 256, 0, stream>>>(
        ei, x, W1, W2, flagE, flagF, cnt, srcu, dstu, rank, xb, wsw1, wsw2);
    scan_blocksum_kernel<<<NBLK, 256, 0, stream>>>(cnt, blockSums);
    scan_apply_kernel<<<NBLK, 256, 0, stream>>>(cnt, blockSums, row_ptr, dinv);
    fill_direct_kernel<<<EGRID, 256, 0, stream>>>(dstu, srcu, rank, row_ptr, dinv,
                                                  csr_src, csr_w);

    // layer 1: aggb = A_hat @ x ; h = relu(aggb @ W1 + b1), bf16 out
    gather_kernel<<<AGRID, 256, 0, stream>>>(xb, row_ptr, csr_src, csr_w, dinv, aggb);
    gemm_mfma_kernel<<<GGRID, 256, 0, stream>>>(aggb, wsw1, b1, flagF, h, 1);

    // layer 2: aggb = A_hat @ h ; out = relu(aggb @ W2 + b2), dtype follows input
    gather_kernel<<<AGRID, 256, 0, stream>>>(h, row_ptr, csr_src, csr_w, dinv, aggb);
    gemm_mfma_kernel<<<GGRID, 256, 0, stream>>>(aggb, wsw2, b2, flagF, d_out, 2);
}

// Round 4
// 209.519 us; speedup vs baseline: 1.0751x; 1.0751x over previous
//
#include <hip/hip_runtime.h>

#define N_NODES 50000
#define N_EDGES 800000
#define DIM 96
#define FEAT_ELEMS (N_NODES * DIM)
#define NBLK 196    // ceil(50000/256)
#define CNT_STRIDE 16            // one counter per 64B line (anti line-lock)
#define CNT_INTS (N_NODES * CNT_STRIDE)   // 800000 ints = 3.2 MB
#define ZBLK4 782   // ceil(200000 int4 stores / 256)
#define EGRID 3125  // 800000/256
#define CGRID 4688  // ceil(FEAT_ELEMS/4/256)
#define WGRID 10    // 2 weight matrices x 5 blocks (1152 frags each)
#define AGRID 3125  // ceil(50000*16/256): 16 lanes per node
#define GGRID 782   // ceil(50000/64)

typedef __attribute__((ext_vector_type(8))) short short8;   // 8 bf16 (4 VGPRs)
typedef __attribute__((ext_vector_type(4))) float float4v;  // 4 fp32 acc

// ---------------------------------------------------------------------------
// bf16 helpers via raw bit ops
// ---------------------------------------------------------------------------
__device__ __forceinline__ float bf16_to_f32(unsigned short u) {
    unsigned int w = ((unsigned int)u) << 16;
    float f;
    __builtin_memcpy(&f, &w, 4);
    return f;
}
__device__ __forceinline__ unsigned short f32_to_bf16_rne(float f) {
    unsigned int w;
    __builtin_memcpy(&w, &f, 4);
    unsigned int r = (w + 0x7FFFu + ((w >> 16) & 1u)) >> 16;
    return (unsigned short)r;
}
__device__ __forceinline__ unsigned int pack_bf16x2(float lo, float hi) {
    return (unsigned int)f32_to_bf16_rne(lo) | ((unsigned int)f32_to_bf16_rne(hi) << 16);
}

__device__ __forceinline__ int edge_at(const void* ep, int is64, int idx) {
    if (is64) return (int)((const long long*)ep)[idx];
    return ((const int*)ep)[idx];
}

// ---------------------------------------------------------------------------
// prolog: blocks [0,ZBLK4) zero the padded cnt array (int4 stores); block
// ZBLK4 detects edge dtype (int64 => odd 32-bit words all zero => flagE=1);
// block ZBLK4+1 detects float dtype of x (bf16 => exponent test => flagF=1).
// ---------------------------------------------------------------------------
__global__ __launch_bounds__(256) void prolog_kernel(const unsigned int* edges,
                                                     const unsigned int* x,
                                                     int* flagE, int* flagF, int* cnt) {
    __shared__ unsigned int sh[256];
    int t = threadIdx.x;
    int b = blockIdx.x;
    if (b < ZBLK4) {
        int i4 = b * 256 + t;
        if (i4 < CNT_INTS / 4) ((int4*)cnt)[i4] = make_int4(0, 0, 0, 0);
        return;
    }
    if (b == ZBLK4) {
        if (t < 64) {
            unsigned int acc = 0;
            for (int k = 0; k < 4; ++k) {
                int idx = t * 4 + k;           // 0..255
                int pos = 1 + 2 * idx * 3109;  // odd words, max 1,585,591 < 1.6M
                acc |= edges[pos];
            }
            sh[t] = acc;
        }
        __syncthreads();
        if (t == 0) {
            unsigned int a = 0;
            for (int i = 0; i < 64; ++i) a |= sh[i];
            *flagE = (a == 0u) ? 1 : 0;
        }
        return;
    }
    // b == ZBLK4+1: feature dtype
    unsigned int w = x[t * 9000];  // max 2,295,000 < 2.4M words (bf16 interp)
    unsigned int e = (w >> 7) & 0xFFu;
    sh[t] = (e >= 100u && e <= 135u) ? 1u : 0u;
    __syncthreads();
    if (t == 0) {
        int c = 0;
        for (int i = 0; i < 256; ++i) c += (int)sh[i];
        *flagF = (c >= 128) ? 1 : 0;
    }
}

// ---------------------------------------------------------------------------
// fused prep: blocks [0,EGRID) count+compact+rank -> one ushort4 record
// {s, d, rank, 0} per edge (single 8B store; counters padded one/64B line);
// [EGRID,EGRID+CGRID) convert x -> bf16; [EGRID+CGRID, +WGRID) build
// B-fragment-swizzled copies of W1/W2 in global memory. Frag
// f=(kt*6+nt)*64+lane holds W[kt*32+(lane>>4)*8+j][nt*16+(lane&15)], j=0..7.
// ---------------------------------------------------------------------------
__global__ __launch_bounds__(256) void count_convert_kernel(const void* __restrict__ edges,
                                                            const void* __restrict__ x,
                                                            const void* __restrict__ W1,
                                                            const void* __restrict__ W2,
                                                            const int* __restrict__ flagE,
                                                            const int* __restrict__ flagF,
                                                            int* __restrict__ cnt,
                                                            ushort4* __restrict__ edata,
                                                            unsigned short* __restrict__ xb,
                                                            unsigned short* __restrict__ wsw1,
                                                            unsigned short* __restrict__ wsw2) {
    int b = blockIdx.x;
    if (b < EGRID) {
        int e = b * 256 + threadIdx.x;  // EGRID*256 == N_EDGES exactly
        int is64 = *flagE;
        int s = edge_at(edges, is64, e);
        int d = edge_at(edges, is64, N_EDGES + e);
        int r = atomicAdd(&cnt[d * CNT_STRIDE], 1);
        edata[e] = make_ushort4((unsigned short)s, (unsigned short)d,
                                (unsigned short)r, 0);
        return;
    }
    if (b < EGRID + CGRID) {
        int i4 = ((b - EGRID) * 256 + threadIdx.x) * 4;
        if (i4 >= FEAT_ELEMS) return;
        int isbf16 = *flagF;
        ushort4 o;
        if (isbf16) {
            o = *(const ushort4*)((const unsigned short*)x + i4);
        } else {
            float4 v = *(const float4*)((const float*)x + i4);
            o.x = f32_to_bf16_rne(v.x);
            o.y = f32_to_bf16_rne(v.y);
            o.z = f32_to_bf16_rne(v.z);
            o.w = f32_to_bf16_rne(v.w);
        }
        *(ushort4*)(xb + i4) = o;
        return;
    }
    // weight swizzle build
    int wi = b - EGRID - CGRID;          // 0..9
    int which = wi / 5;                  // 0 -> W1, 1 -> W2
    int f = (wi - which * 5) * 256 + threadIdx.x;
    if (f >= 1152) return;
    const void* Wp = which ? W2 : W1;
    unsigned short* Op = which ? wsw2 : wsw1;
    int wBf16 = *flagF;
    int kt = f / 384;
    int rem = f - kt * 384;
    int nt = rem >> 6;
    int ln64 = rem & 63;
    int q = ln64 >> 4, ln = ln64 & 15;
    int k0 = kt * 32 + q * 8;
    int n = nt * 16 + ln;
    unsigned short e[8];
    if (wBf16) {
        const unsigned short* Wh = (const unsigned short*)Wp;
        #pragma unroll
        for (int j = 0; j < 8; ++j) e[j] = Wh[(k0 + j) * DIM + n];
    } else {
        const float* Wf = (const float*)Wp;
        #pragma unroll
        for (int j = 0; j < 8; ++j) e[j] = f32_to_bf16_rne(Wf[(k0 + j) * DIM + n]);
    }
    uint4 pk;
    pk.x = (unsigned int)e[0] | ((unsigned int)e[1] << 16);
    pk.y = (unsigned int)e[2] | ((unsigned int)e[3] << 16);
    pk.z = (unsigned int)e[4] | ((unsigned int)e[5] << 16);
    pk.w = (unsigned int)e[6] | ((unsigned int)e[7] << 16);
    *(uint4*)&Op[f * 8] = pk;
}

// ---------------------------------------------------------------------------
// scan phase 1: per-block sums of cnt (strided reads of padded counters)
// ---------------------------------------------------------------------------
__global__ __launch_bounds__(256) void scan_blocksum_kernel(const int* cnt, int* blockSums) {
    __shared__ int sh[256];
    int i = blockIdx.x * 256 + threadIdx.x;
    sh[threadIdx.x] = (i < N_NODES) ? cnt[i * CNT_STRIDE] : 0;
    __syncthreads();
    for (int off = 128; off > 0; off >>= 1) {
        if (threadIdx.x < off) sh[threadIdx.x] += sh[threadIdx.x + off];
        __syncthreads();
    }
    if (threadIdx.x == 0) blockSums[blockIdx.x] = sh[0];
}

// ---------------------------------------------------------------------------
// scan phase 2 (merged offsets+apply): every block redundantly scans the 196
// block sums in LDS, derives its own exclusive offset, then scans its 256
// cnt entries -> row_ptr (+ dinv). Block 0 thread 0 writes the total.
// ---------------------------------------------------------------------------
__global__ __launch_bounds__(256) void scan_apply_kernel(const int* __restrict__ cnt,
                                                         const int* __restrict__ blockSums,
                                                         int* __restrict__ row_ptr,
                                                         float* __restrict__ dinv) {
    __shared__ int sb[256];
    __shared__ int sh[256];
    int t = threadIdx.x;
    sb[t] = (t < NBLK) ? blockSums[t] : 0;
    __syncthreads();
    for (int off = 1; off < 256; off <<= 1) {
        int u = (t >= off) ? sb[t - off] : 0;
        __syncthreads();
        sb[t] += u;
        __syncthreads();
    }
    int b = blockIdx.x;
    int blockOff = (b == 0) ? 0 : sb[b - 1];  // exclusive prefix of this block
    if (b == 0 && t == 0) row_ptr[N_NODES] = sb[NBLK - 1];

    int i = b * 256 + t;
    int c = (i < N_NODES) ? cnt[i * CNT_STRIDE] : 0;
    sh[t] = c;
    __syncthreads();
    for (int off = 1; off < 256; off <<= 1) {
        int u = (t >= off) ? sh[t - off] : 0;
        __syncthreads();
        sh[t] += u;
        __syncthreads();
    }
    if (i < N_NODES) {
        row_ptr[i] = sh[t] - c + blockOff;
        dinv[i]    = rsqrtf((float)(c + 1));  // +1 self-loop
    }
}

// ---------------------------------------------------------------------------
// fill (rank-based direct scatter, NO atomics). One coalesced 8B read of
// {s,d,rank}, one scattered 8B store of {src, w=dinv[s]*dinv[d]} -> a single
// random line touched per edge (was two: csr_src 2B + csr_w 4B).
// ---------------------------------------------------------------------------
__global__ __launch_bounds__(256) void fill_direct_kernel(const ushort4* __restrict__ edata,
                                                          const int* __restrict__ row_ptr,
                                                          const float* __restrict__ dinv,
                                                          uint2* __restrict__ csr8) {
    int e = blockIdx.x * 256 + threadIdx.x;
    if (e >= N_EDGES) return;
    ushort4 ed = edata[e];
    int s = ed.x, d = ed.y;
    int pos = row_ptr[d] + (int)ed.z;
    float w = dinv[s] * dinv[d];
    csr8[pos] = make_uint2((unsigned int)s, __float_as_uint(w));
}

// ---------------------------------------------------------------------------
// Gather-aggregate (bf16 feat, fp32 accum, bf16 out): 16 lanes per node,
// 6 dims per lane (3x ushort2), 800k threads, no LDS -> full occupancy.
// 4-edge unroll: 12 independent feat loads + 4 broadcast csr8 loads in
// flight per lane per iteration (r2-proven structure, fewer requests).
// ---------------------------------------------------------------------------
__global__ __launch_bounds__(256) void gather_kernel(const unsigned short* __restrict__ feat,
                                                     const int* __restrict__ row_ptr,
                                                     const uint2* __restrict__ csr8,
                                                     const float* __restrict__ dinv,
                                                     unsigned short* __restrict__ aggb) {
    int gid = blockIdx.x * 256 + threadIdx.x;
    int g = gid >> 4;
    int l = gid & 15;
    if (g >= N_NODES) return;
    float di = dinv[g];
    int gb = g * DIM + l * 2;
    ushort2 sv0 = *(const ushort2*)&feat[gb];
    ushort2 sv1 = *(const ushort2*)&feat[gb + 32];
    ushort2 sv2 = *(const ushort2*)&feat[gb + 64];
    float wself = di * di;
    float a0 = wself * bf16_to_f32(sv0.x), a1 = wself * bf16_to_f32(sv0.y);
    float a2 = wself * bf16_to_f32(sv1.x), a3 = wself * bf16_to_f32(sv1.y);
    float a4 = wself * bf16_to_f32(sv2.x), a5 = wself * bf16_to_f32(sv2.y);
    int e = row_ptr[g], e1 = row_ptr[g + 1];
    for (; e + 4 <= e1; e += 4) {
        uint2 c0 = csr8[e + 0];
        uint2 c1 = csr8[e + 1];
        uint2 c2 = csr8[e + 2];
        uint2 c3 = csr8[e + 3];
        int b0 = (int)(c0.x & 0xFFFFu) * DIM + l * 2;
        int b1 = (int)(c1.x & 0xFFFFu) * DIM + l * 2;
        int b2 = (int)(c2.x & 0xFFFFu) * DIM + l * 2;
        int b3 = (int)(c3.x & 0xFFFFu) * DIM + l * 2;
        float w0 = __uint_as_float(c0.y);
        float w1 = __uint_as_float(c1.y);
        float w2 = __uint_as_float(c2.y);
        float w3 = __uint_as_float(c3.y);
        ushort2 p0 = *(const ushort2*)&feat[b0];
        ushort2 p1 = *(const ushort2*)&feat[b0 + 32];
        ushort2 p2 = *(const ushort2*)&feat[b0 + 64];
        ushort2 q0 = *(const ushort2*)&feat[b1];
        ushort2 q1 = *(const ushort2*)&feat[b1 + 32];
        ushort2 q2 = *(const ushort2*)&feat[b1 + 64];
        ushort2 r0 = *(const ushort2*)&feat[b2];
        ushort2 r1 = *(const ushort2*)&feat[b2 + 32];
        ushort2 r2 = *(const ushort2*)&feat[b2 + 64];
        ushort2 t0 = *(const ushort2*)&feat[b3];
        ushort2 t1 = *(const ushort2*)&feat[b3 + 32];
        ushort2 t2 = *(const ushort2*)&feat[b3 + 64];
        a0 = fmaf(w0, bf16_to_f32(p0.x), a0);  a1 = fmaf(w0, bf16_to_f32(p0.y), a1);
        a2 = fmaf(w0, bf16_to_f32(p1.x), a2);  a3 = fmaf(w0, bf16_to_f32(p1.y), a3);
        a4 = fmaf(w0, bf16_to_f32(p2.x), a4);  a5 = fmaf(w0, bf16_to_f32(p2.y), a5);
        a0 = fmaf(w1, bf16_to_f32(q0.x), a0);  a1 = fmaf(w1, bf16_to_f32(q0.y), a1);
        a2 = fmaf(w1, bf16_to_f32(q1.x), a2);  a3 = fmaf(w1, bf16_to_f32(q1.y), a3);
        a4 = fmaf(w1, bf16_to_f32(q2.x), a4);  a5 = fmaf(w1, bf16_to_f32(q2.y), a5);
        a0 = fmaf(w2, bf16_to_f32(r0.x), a0);  a1 = fmaf(w2, bf16_to_f32(r0.y), a1);
        a2 = fmaf(w2, bf16_to_f32(r1.x), a2);  a3 = fmaf(w2, bf16_to_f32(r1.y), a3);
        a4 = fmaf(w2, bf16_to_f32(r2.x), a4);  a5 = fmaf(w2, bf16_to_f32(r2.y), a5);
        a0 = fmaf(w3, bf16_to_f32(t0.x), a0);  a1 = fmaf(w3, bf16_to_f32(t0.y), a1);
        a2 = fmaf(w3, bf16_to_f32(t1.x), a2);  a3 = fmaf(w3, bf16_to_f32(t1.y), a3);
        a4 = fmaf(w3, bf16_to_f32(t2.x), a4);  a5 = fmaf(w3, bf16_to_f32(t2.y), a5);
    }
    for (; e < e1; ++e) {
        uint2 c = csr8[e];
        int b0 = (int)(c.x & 0xFFFFu) * DIM + l * 2;
        float w = __uint_as_float(c.y);
        ushort2 p0 = *(const ushort2*)&feat[b0];
        ushort2 p1 = *(const ushort2*)&feat[b0 + 32];
        ushort2 p2 = *(const ushort2*)&feat[b0 + 64];
        a0 = fmaf(w, bf16_to_f32(p0.x), a0);  a1 = fmaf(w, bf16_to_f32(p0.y), a1);
        a2 = fmaf(w, bf16_to_f32(p1.x), a2);  a3 = fmaf(w, bf16_to_f32(p1.y), a3);
        a4 = fmaf(w, bf16_to_f32(p2.x), a4);  a5 = fmaf(w, bf16_to_f32(p2.y), a5);
    }
    *(unsigned int*)&aggb[gb]      = pack_bf16x2(a0, a1);
    *(unsigned int*)&aggb[gb + 32] = pack_bf16x2(a2, a3);
    *(unsigned int*)&aggb[gb + 64] = pack_bf16x2(a4, a5);
}

// ---------------------------------------------------------------------------
// MFMA GEMM + bias + ReLU, NO LDS / NO syncs: out[M,96] = relu(A @ W + b).
// A bf16 [N_NODES,96]; Wsw pre-swizzled B-fragment table in global (18 KB,
// L2-broadcast). mfma_f32_16x16x32_bf16, K=3x32. 256 thr = 4 waves x 16 rows.
// C/D: col=lane&15, row=(lane>>4)*4+reg. outMode: 0=fp32,1=bf16,2=follow flagF
// ---------------------------------------------------------------------------
__global__ __launch_bounds__(256) void gemm_mfma_kernel(const unsigned short* __restrict__ A,
                                                        const unsigned short* __restrict__ Wsw,
                                                        const void* __restrict__ bias,
                                                        const int* __restrict__ flagF,
                                                        void* __restrict__ out, int outMode) {
    int wBf16 = *flagF;
    int outBf16 = (outMode == 2) ? wBf16 : outMode;
    int t = threadIdx.x;
    int wave = t >> 6;
    int lane = t & 63;
    int quad = lane >> 4, ln = lane & 15;
    int m0 = blockIdx.x * 64 + wave * 16;
    int arow = m0 + ln;
    bool arowok = (arow < N_NODES);

    float4v acc[6];
    #pragma unroll
    for (int nt = 0; nt < 6; ++nt) acc[nt] = (float4v){0.f, 0.f, 0.f, 0.f};

    #pragma unroll
    for (int kt = 0; kt < 3; ++kt) {
        short8 af;
        if (arowok) {
            af = *(const short8*)&A[arow * DIM + kt * 32 + quad * 8];
        } else {
            af = (short8){0, 0, 0, 0, 0, 0, 0, 0};
        }
        #pragma unroll
        for (int nt = 0; nt < 6; ++nt) {
            short8 bf = *(const short8*)&Wsw[((kt * 6 + nt) * 64 + lane) * 8];
            acc[nt] = __builtin_amdgcn_mfma_f32_16x16x32_bf16(af, bf, acc[nt], 0, 0, 0);
        }
    }

    #pragma unroll
    for (int nt = 0; nt < 6; ++nt) {
        int n = nt * 16 + ln;
        float bv = wBf16 ? bf16_to_f32(((const unsigned short*)bias)[n])
                         : ((const float*)bias)[n];
        #pragma unroll
        for (int reg = 0; reg < 4; ++reg) {
            int row = m0 + quad * 4 + reg;
            if (row >= N_NODES) continue;
            float v = fmaxf(acc[nt][reg] + bv, 0.0f);
            if (outBf16) ((unsigned short*)out)[row * DIM + n] = f32_to_bf16_rne(v);
            else         ((float*)out)[row * DIM + n] = v;
        }
    }
}

// ---------------------------------------------------------------------------
extern "C" void kernel_launch(void* const* d_in, const int* in_sizes, int n_in,
                              void* d_out, int out_size, void* d_ws, size_t ws_size,
                              hipStream_t stream) {
    const void* x  = d_in[0];
    const void* ei = d_in[1];
    const void* W1 = d_in[2];
    const void* b1 = d_in[3];
    const void* W2 = d_in[4];
    const void* b2 = d_in[5];

    char* base = (char*)d_ws;
    size_t off = 0;
    auto carve = [&](size_t bytes) -> void* {
        void* p = base + off;
        off += (bytes + 255) & ~(size_t)255;
        return p;
    };
    int*            flagE     = (int*)carve(4);
    int*            flagF     = (int*)carve(4);
    int*            cnt       = (int*)carve((size_t)CNT_INTS * 4);  // 3.2 MB padded
    int*            row_ptr   = (int*)carve((size_t)(N_NODES + 1) * 4);
    float*          dinv      = (float*)carve((size_t)N_NODES * 4);
    int*            blockSums = (int*)carve((size_t)NBLK * 4);
    ushort4*        edata     = (ushort4*)carve((size_t)N_EDGES * 8);
    uint2*          csr8      = (uint2*)carve((size_t)N_EDGES * 8);
    unsigned short* wsw1      = (unsigned short*)carve((size_t)1152 * 8 * 2);
    unsigned short* wsw2      = (unsigned short*)carve((size_t)1152 * 8 * 2);
    unsigned short* aggb      = (unsigned short*)carve((size_t)FEAT_ELEMS * 2);
    unsigned short* xb        = (unsigned short*)carve((size_t)FEAT_ELEMS * 2);
    unsigned short* h         = (unsigned short*)carve((size_t)FEAT_ELEMS * 2);

    prolog_kernel<<<ZBLK4 + 2, 256, 0, stream>>>((const unsigned int*)ei,
                                                 (const unsigned int*)x, flagE, flagF, cnt);
    count_convert_kernel<<<EGRID + CGRID + WGRID, 256, 0, stream>>>(
        ei, x, W1, W2, flagE, flagF, cnt, edata, xb, wsw1, wsw2);
    scan_blocksum_kernel<<<NBLK, 256, 0, stream>>>(cnt, blockSums);
    scan_apply_kernel<<<NBLK, 256, 0, stream>>>(cnt, blockSums, row_ptr, dinv);
    fill_direct_kernel<<<EGRID, 256, 0, stream>>>(edata, row_ptr, dinv, csr8);

    // layer 1: aggb = A_hat @ x ; h = relu(aggb @ W1 + b1), bf16 out
    gather_kernel<<<AGRID, 256, 0, stream>>>(xb, row_ptr, csr8, dinv, aggb);
    gemm_mfma_kernel<<<GGRID, 256, 0, stream>>>(aggb, wsw1, b1, flagF, h, 1);

    // layer 2: aggb = A_hat @ h ; out = relu(aggb @ W2 + b2), dtype follows input
    gather_kernel<<<AGRID, 256, 0, stream>>>(h, row_ptr, csr8, dinv, aggb);
    gemm_mfma_kernel<<<GGRID, 256, 0, stream>>>(aggb, wsw2, b2, flagF, d_out, 2);
}

// Round 5
// 209.311 us; speedup vs baseline: 1.0762x; 1.0010x over previous
//
#include <hip/hip_runtime.h>

#define N_NODES 50000
#define N_EDGES 800000
#define DIM 96
#define FEAT_ELEMS (N_NODES * DIM)
#define NBLK 196    // ceil(50000/256)
#define CNT_STRIDE 16            // one counter per 64B line (anti line-lock)
#define CNT_INTS (N_NODES * CNT_STRIDE)   // 800000 ints = 3.2 MB
#define ZBLK4 782   // ceil(200000 int4 stores / 256)
#define EGRID 3125  // 800000/256
#define CGRID 4688  // ceil(FEAT_ELEMS/4/256)
#define WGRID 10    // 2 weight matrices x 5 blocks (1152 frags each)
#define AGRID 3125  // ceil(50000*16/256): 16 lanes per node
#define GGRID 782   // ceil(50000/64)

typedef __attribute__((ext_vector_type(8))) short short8;   // 8 bf16 (4 VGPRs)
typedef __attribute__((ext_vector_type(4))) float float4v;  // 4 fp32 acc

// ---------------------------------------------------------------------------
// bf16 helpers via raw bit ops
// ---------------------------------------------------------------------------
__device__ __forceinline__ float bf16_to_f32(unsigned short u) {
    unsigned int w = ((unsigned int)u) << 16;
    float f;
    __builtin_memcpy(&f, &w, 4);
    return f;
}
// low/high bf16 of a packed dword -> f32 (1 VALU op each)
__device__ __forceinline__ float bflo(unsigned int w) {
    unsigned int u = w << 16;
    float f;
    __builtin_memcpy(&f, &u, 4);
    return f;
}
__device__ __forceinline__ float bfhi(unsigned int w) {
    unsigned int u = w & 0xFFFF0000u;
    float f;
    __builtin_memcpy(&f, &u, 4);
    return f;
}
__device__ __forceinline__ unsigned short f32_to_bf16_rne(float f) {
    unsigned int w;
    __builtin_memcpy(&w, &f, 4);
    unsigned int r = (w + 0x7FFFu + ((w >> 16) & 1u)) >> 16;
    return (unsigned short)r;
}
__device__ __forceinline__ unsigned int pack_bf16x2(float lo, float hi) {
    return (unsigned int)f32_to_bf16_rne(lo) | ((unsigned int)f32_to_bf16_rne(hi) << 16);
}

__device__ __forceinline__ int edge_at(const void* ep, int is64, int idx) {
    if (is64) return (int)((const long long*)ep)[idx];
    return ((const int*)ep)[idx];
}

// ---------------------------------------------------------------------------
// prolog: blocks [0,ZBLK4) zero the padded cnt array (int4 stores); block
// ZBLK4 detects edge dtype (int64 => odd 32-bit words all zero => flagE=1);
// block ZBLK4+1 detects float dtype of x (bf16 => exponent test => flagF=1).
// ---------------------------------------------------------------------------
__global__ __launch_bounds__(256) void prolog_kernel(const unsigned int* edges,
                                                     const unsigned int* x,
                                                     int* flagE, int* flagF, int* cnt) {
    __shared__ unsigned int sh[256];
    int t = threadIdx.x;
    int b = blockIdx.x;
    if (b < ZBLK4) {
        int i4 = b * 256 + t;
        if (i4 < CNT_INTS / 4) ((int4*)cnt)[i4] = make_int4(0, 0, 0, 0);
        return;
    }
    if (b == ZBLK4) {
        if (t < 64) {
            unsigned int acc = 0;
            for (int k = 0; k < 4; ++k) {
                int idx = t * 4 + k;           // 0..255
                int pos = 1 + 2 * idx * 3109;  // odd words, max 1,585,591 < 1.6M
                acc |= edges[pos];
            }
            sh[t] = acc;
        }
        __syncthreads();
        if (t == 0) {
            unsigned int a = 0;
            for (int i = 0; i < 64; ++i) a |= sh[i];
            *flagE = (a == 0u) ? 1 : 0;
        }
        return;
    }
    // b == ZBLK4+1: feature dtype
    unsigned int w = x[t * 9000];  // max 2,295,000 < 2.4M words (bf16 interp)
    unsigned int e = (w >> 7) & 0xFFu;
    sh[t] = (e >= 100u && e <= 135u) ? 1u : 0u;
    __syncthreads();
    if (t == 0) {
        int c = 0;
        for (int i = 0; i < 256; ++i) c += (int)sh[i];
        *flagF = (c >= 128) ? 1 : 0;
    }
}

// ---------------------------------------------------------------------------
// fused prep: blocks [0,EGRID) count+compact+rank -> one ushort4 record
// {s, d, rank, 0} per edge (single 8B store; counters padded one/64B line);
// [EGRID,EGRID+CGRID) convert x -> bf16; [EGRID+CGRID, +WGRID) build
// B-fragment-swizzled copies of W1/W2 in global memory. Frag
// f=(kt*6+nt)*64+lane holds W[kt*32+(lane>>4)*8+j][nt*16+(lane&15)], j=0..7.
// ---------------------------------------------------------------------------
__global__ __launch_bounds__(256) void count_convert_kernel(const void* __restrict__ edges,
                                                            const void* __restrict__ x,
                                                            const void* __restrict__ W1,
                                                            const void* __restrict__ W2,
                                                            const int* __restrict__ flagE,
                                                            const int* __restrict__ flagF,
                                                            int* __restrict__ cnt,
                                                            ushort4* __restrict__ edata,
                                                            unsigned short* __restrict__ xb,
                                                            unsigned short* __restrict__ wsw1,
                                                            unsigned short* __restrict__ wsw2) {
    int b = blockIdx.x;
    if (b < EGRID) {
        int e = b * 256 + threadIdx.x;  // EGRID*256 == N_EDGES exactly
        int is64 = *flagE;
        int s = edge_at(edges, is64, e);
        int d = edge_at(edges, is64, N_EDGES + e);
        int r = atomicAdd(&cnt[d * CNT_STRIDE], 1);
        edata[e] = make_ushort4((unsigned short)s, (unsigned short)d,
                                (unsigned short)r, 0);
        return;
    }
    if (b < EGRID + CGRID) {
        int i4 = ((b - EGRID) * 256 + threadIdx.x) * 4;
        if (i4 >= FEAT_ELEMS) return;
        int isbf16 = *flagF;
        ushort4 o;
        if (isbf16) {
            o = *(const ushort4*)((const unsigned short*)x + i4);
        } else {
            float4 v = *(const float4*)((const float*)x + i4);
            o.x = f32_to_bf16_rne(v.x);
            o.y = f32_to_bf16_rne(v.y);
            o.z = f32_to_bf16_rne(v.z);
            o.w = f32_to_bf16_rne(v.w);
        }
        *(ushort4*)(xb + i4) = o;
        return;
    }
    // weight swizzle build
    int wi = b - EGRID - CGRID;          // 0..9
    int which = wi / 5;                  // 0 -> W1, 1 -> W2
    int f = (wi - which * 5) * 256 + threadIdx.x;
    if (f >= 1152) return;
    const void* Wp = which ? W2 : W1;
    unsigned short* Op = which ? wsw2 : wsw1;
    int wBf16 = *flagF;
    int kt = f / 384;
    int rem = f - kt * 384;
    int nt = rem >> 6;
    int ln64 = rem & 63;
    int q = ln64 >> 4, ln = ln64 & 15;
    int k0 = kt * 32 + q * 8;
    int n = nt * 16 + ln;
    unsigned short e[8];
    if (wBf16) {
        const unsigned short* Wh = (const unsigned short*)Wp;
        #pragma unroll
        for (int j = 0; j < 8; ++j) e[j] = Wh[(k0 + j) * DIM + n];
    } else {
        const float* Wf = (const float*)Wp;
        #pragma unroll
        for (int j = 0; j < 8; ++j) e[j] = f32_to_bf16_rne(Wf[(k0 + j) * DIM + n]);
    }
    uint4 pk;
    pk.x = (unsigned int)e[0] | ((unsigned int)e[1] << 16);
    pk.y = (unsigned int)e[2] | ((unsigned int)e[3] << 16);
    pk.z = (unsigned int)e[4] | ((unsigned int)e[5] << 16);
    pk.w = (unsigned int)e[6] | ((unsigned int)e[7] << 16);
    *(uint4*)&Op[f * 8] = pk;
}

// ---------------------------------------------------------------------------
// scan phase 1: per-block sums of cnt (strided reads of padded counters)
// ---------------------------------------------------------------------------
__global__ __launch_bounds__(256) void scan_blocksum_kernel(const int* cnt, int* blockSums) {
    __shared__ int sh[256];
    int i = blockIdx.x * 256 + threadIdx.x;
    sh[threadIdx.x] = (i < N_NODES) ? cnt[i * CNT_STRIDE] : 0;
    __syncthreads();
    for (int off = 128; off > 0; off >>= 1) {
        if (threadIdx.x < off) sh[threadIdx.x] += sh[threadIdx.x + off];
        __syncthreads();
    }
    if (threadIdx.x == 0) blockSums[blockIdx.x] = sh[0];
}

// ---------------------------------------------------------------------------
// scan phase 2 (merged offsets+apply): every block redundantly scans the 196
// block sums in LDS, derives its own exclusive offset, then scans its 256
// cnt entries -> row_ptr (+ dinv). Block 0 thread 0 writes the total.
// ---------------------------------------------------------------------------
__global__ __launch_bounds__(256) void scan_apply_kernel(const int* __restrict__ cnt,
                                                         const int* __restrict__ blockSums,
                                                         int* __restrict__ row_ptr,
                                                         float* __restrict__ dinv) {
    __shared__ int sb[256];
    __shared__ int sh[256];
    int t = threadIdx.x;
    sb[t] = (t < NBLK) ? blockSums[t] : 0;
    __syncthreads();
    for (int off = 1; off < 256; off <<= 1) {
        int u = (t >= off) ? sb[t - off] : 0;
        __syncthreads();
        sb[t] += u;
        __syncthreads();
    }
    int b = blockIdx.x;
    int blockOff = (b == 0) ? 0 : sb[b - 1];  // exclusive prefix of this block
    if (b == 0 && t == 0) row_ptr[N_NODES] = sb[NBLK - 1];

    int i = b * 256 + t;
    int c = (i < N_NODES) ? cnt[i * CNT_STRIDE] : 0;
    sh[t] = c;
    __syncthreads();
    for (int off = 1; off < 256; off <<= 1) {
        int u = (t >= off) ? sh[t - off] : 0;
        __syncthreads();
        sh[t] += u;
        __syncthreads();
    }
    if (i < N_NODES) {
        row_ptr[i] = sh[t] - c + blockOff;
        dinv[i]    = rsqrtf((float)(c + 1));  // +1 self-loop
    }
}

// ---------------------------------------------------------------------------
// fill (rank-based direct scatter, NO atomics). One coalesced 8B read of
// {s,d,rank}, one scattered 8B store of {src, w=dinv[s]*dinv[d]}.
// ---------------------------------------------------------------------------
__global__ __launch_bounds__(256) void fill_direct_kernel(const ushort4* __restrict__ edata,
                                                          const int* __restrict__ row_ptr,
                                                          const float* __restrict__ dinv,
                                                          uint2* __restrict__ csr8) {
    int e = blockIdx.x * 256 + threadIdx.x;
    if (e >= N_EDGES) return;
    ushort4 ed = edata[e];
    int s = ed.x, d = ed.y;
    int pos = row_ptr[d] + (int)ed.z;
    float w = dinv[s] * dinv[d];
    csr8[pos] = make_uint2((unsigned int)s, __float_as_uint(w));
}

// ---------------------------------------------------------------------------
// Gather-aggregate (bf16 feat, fp32 accum, bf16 out): 16 lanes per node,
// lane l owns dims [6l, 6l+6). A row is 192 B = 16 lanes x 12 B, so ONE
// dwordx3 per edge per group fetches the whole row (was 3 ushort2 loads).
// 4-edge unroll -> 4 row-loads + 4 csr8 loads in flight. Unpack: hi bf16 of
// a dword is (w & 0xFFFF0000) reinterpret; lo is (w<<16) -- 1 VALU op each.
// Output layout unchanged (row-major), so the GEMM is untouched.
// ---------------------------------------------------------------------------
__global__ __launch_bounds__(256) void gather_kernel(const unsigned short* __restrict__ feat,
                                                     const int* __restrict__ row_ptr,
                                                     const uint2* __restrict__ csr8,
                                                     const float* __restrict__ dinv,
                                                     unsigned short* __restrict__ aggb) {
    int gid = blockIdx.x * 256 + threadIdx.x;
    int g = gid >> 4;
    int l = gid & 15;
    if (g >= N_NODES) return;
    float di = dinv[g];
    const unsigned int* sp = (const unsigned int*)(feat + g * DIM + l * 6);
    unsigned int sw0 = sp[0], sw1 = sp[1], sw2 = sp[2];
    float wself = di * di;
    float a0 = wself * bflo(sw0), a1 = wself * bfhi(sw0);
    float a2 = wself * bflo(sw1), a3 = wself * bfhi(sw1);
    float a4 = wself * bflo(sw2), a5 = wself * bfhi(sw2);
    int e = row_ptr[g], e1 = row_ptr[g + 1];
    for (; e + 4 <= e1; e += 4) {
        uint2 c0 = csr8[e + 0];
        uint2 c1 = csr8[e + 1];
        uint2 c2 = csr8[e + 2];
        uint2 c3 = csr8[e + 3];
        const unsigned int* p = (const unsigned int*)(feat + (c0.x & 0xFFFFu) * DIM + l * 6);
        const unsigned int* q = (const unsigned int*)(feat + (c1.x & 0xFFFFu) * DIM + l * 6);
        const unsigned int* r = (const unsigned int*)(feat + (c2.x & 0xFFFFu) * DIM + l * 6);
        const unsigned int* s = (const unsigned int*)(feat + (c3.x & 0xFFFFu) * DIM + l * 6);
        unsigned int p0 = p[0], p1 = p[1], p2 = p[2];
        unsigned int q0 = q[0], q1 = q[1], q2 = q[2];
        unsigned int r0 = r[0], r1 = r[1], r2 = r[2];
        unsigned int s0 = s[0], s1 = s[1], s2 = s[2];
        float w0 = __uint_as_float(c0.y);
        float w1 = __uint_as_float(c1.y);
        float w2 = __uint_as_float(c2.y);
        float w3 = __uint_as_float(c3.y);
        a0 = fmaf(w0, bflo(p0), a0);  a1 = fmaf(w0, bfhi(p0), a1);
        a2 = fmaf(w0, bflo(p1), a2);  a3 = fmaf(w0, bfhi(p1), a3);
        a4 = fmaf(w0, bflo(p2), a4);  a5 = fmaf(w0, bfhi(p2), a5);
        a0 = fmaf(w1, bflo(q0), a0);  a1 = fmaf(w1, bfhi(q0), a1);
        a2 = fmaf(w1, bflo(q1), a2);  a3 = fmaf(w1, bfhi(q1), a3);
        a4 = fmaf(w1, bflo(q2), a4);  a5 = fmaf(w1, bfhi(q2), a5);
        a0 = fmaf(w2, bflo(r0), a0);  a1 = fmaf(w2, bfhi(r0), a1);
        a2 = fmaf(w2, bflo(r1), a2);  a3 = fmaf(w2, bfhi(r1), a3);
        a4 = fmaf(w2, bflo(r2), a4);  a5 = fmaf(w2, bfhi(r2), a5);
        a0 = fmaf(w3, bflo(s0), a0);  a1 = fmaf(w3, bfhi(s0), a1);
        a2 = fmaf(w3, bflo(s1), a2);  a3 = fmaf(w3, bfhi(s1), a3);
        a4 = fmaf(w3, bflo(s2), a4);  a5 = fmaf(w3, bfhi(s2), a5);
    }
    for (; e < e1; ++e) {
        uint2 c = csr8[e];
        const unsigned int* p = (const unsigned int*)(feat + (c.x & 0xFFFFu) * DIM + l * 6);
        unsigned int p0 = p[0], p1 = p[1], p2 = p[2];
        float w = __uint_as_float(c.y);
        a0 = fmaf(w, bflo(p0), a0);  a1 = fmaf(w, bfhi(p0), a1);
        a2 = fmaf(w, bflo(p1), a2);  a3 = fmaf(w, bfhi(p1), a3);
        a4 = fmaf(w, bflo(p2), a4);  a5 = fmaf(w, bfhi(p2), a5);
    }
    unsigned int* op = (unsigned int*)(aggb + g * DIM + l * 6);
    op[0] = pack_bf16x2(a0, a1);
    op[1] = pack_bf16x2(a2, a3);
    op[2] = pack_bf16x2(a4, a5);
}

// ---------------------------------------------------------------------------
// MFMA GEMM + bias + ReLU, NO LDS / NO syncs: out[M,96] = relu(A @ W + b).
// A bf16 [N_NODES,96]; Wsw pre-swizzled B-fragment table in global (18 KB,
// L2-broadcast). mfma_f32_16x16x32_bf16, K=3x32. 256 thr = 4 waves x 16 rows.
// C/D: col=lane&15, row=(lane>>4)*4+reg. outMode: 0=fp32,1=bf16,2=follow flagF
// ---------------------------------------------------------------------------
__global__ __launch_bounds__(256) void gemm_mfma_kernel(const unsigned short* __restrict__ A,
                                                        const unsigned short* __restrict__ Wsw,
                                                        const void* __restrict__ bias,
                                                        const int* __restrict__ flagF,
                                                        void* __restrict__ out, int outMode) {
    int wBf16 = *flagF;
    int outBf16 = (outMode == 2) ? wBf16 : outMode;
    int t = threadIdx.x;
    int wave = t >> 6;
    int lane = t & 63;
    int quad = lane >> 4, ln = lane & 15;
    int m0 = blockIdx.x * 64 + wave * 16;
    int arow = m0 + ln;
    bool arowok = (arow < N_NODES);

    float4v acc[6];
    #pragma unroll
    for (int nt = 0; nt < 6; ++nt) acc[nt] = (float4v){0.f, 0.f, 0.f, 0.f};

    #pragma unroll
    for (int kt = 0; kt < 3; ++kt) {
        short8 af;
        if (arowok) {
            af = *(const short8*)&A[arow * DIM + kt * 32 + quad * 8];
        } else {
            af = (short8){0, 0, 0, 0, 0, 0, 0, 0};
        }
        #pragma unroll
        for (int nt = 0; nt < 6; ++nt) {
            short8 bf = *(const short8*)&Wsw[((kt * 6 + nt) * 64 + lane) * 8];
            acc[nt] = __builtin_amdgcn_mfma_f32_16x16x32_bf16(af, bf, acc[nt], 0, 0, 0);
        }
    }

    #pragma unroll
    for (int nt = 0; nt < 6; ++nt) {
        int n = nt * 16 + ln;
        float bv = wBf16 ? bf16_to_f32(((const unsigned short*)bias)[n])
                         : ((const float*)bias)[n];
        #pragma unroll
        for (int reg = 0; reg < 4; ++reg) {
            int row = m0 + quad * 4 + reg;
            if (row >= N_NODES) continue;
            float v = fmaxf(acc[nt][reg] + bv, 0.0f);
            if (outBf16) ((unsigned short*)out)[row * DIM + n] = f32_to_bf16_rne(v);
            else         ((float*)out)[row * DIM + n] = v;
        }
    }
}

// ---------------------------------------------------------------------------
extern "C" void kernel_launch(void* const* d_in, const int* in_sizes, int n_in,
                              void* d_out, int out_size, void* d_ws, size_t ws_size,
                              hipStream_t stream) {
    const void* x  = d_in[0];
    const void* ei = d_in[1];
    const void* W1 = d_in[2];
    const void* b1 = d_in[3];
    const void* W2 = d_in[4];
    const void* b2 = d_in[5];

    char* base = (char*)d_ws;
    size_t off = 0;
    auto carve = [&](size_t bytes) -> void* {
        void* p = base + off;
        off += (bytes + 255) & ~(size_t)255;
        return p;
    };
    int*            flagE     = (int*)carve(4);
    int*            flagF     = (int*)carve(4);
    int*            cnt       = (int*)carve((size_t)CNT_INTS * 4);  // 3.2 MB padded
    int*            row_ptr   = (int*)carve((size_t)(N_NODES + 1) * 4);
    float*          dinv      = (float*)carve((size_t)N_NODES * 4);
    int*            blockSums = (int*)carve((size_t)NBLK * 4);
    ushort4*        edata     = (ushort4*)carve((size_t)N_EDGES * 8);
    uint2*          csr8      = (uint2*)carve((size_t)N_EDGES * 8);
    unsigned short* wsw1      = (unsigned short*)carve((size_t)1152 * 8 * 2);
    unsigned short* wsw2      = (unsigned short*)carve((size_t)1152 * 8 * 2);
    unsigned short* aggb      = (unsigned short*)carve((size_t)FEAT_ELEMS * 2);
    unsigned short* xb        = (unsigned short*)carve((size_t)FEAT_ELEMS * 2);
    unsigned short* h         = (unsigned short*)carve((size_t)FEAT_ELEMS * 2);

    prolog_kernel<<<ZBLK4 + 2, 256, 0, stream>>>((const unsigned int*)ei,
                                                 (const unsigned int*)x, flagE, flagF, cnt);
    count_convert_kernel<<<EGRID + CGRID + WGRID, 256, 0, stream>>>(
        ei, x, W1, W2, flagE, flagF, cnt, edata, xb, wsw1, wsw2);
    scan_blocksum_kernel<<<NBLK, 256, 0, stream>>>(cnt, blockSums);
    scan_apply_kernel<<<NBLK, 256, 0, stream>>>(cnt, blockSums, row_ptr, dinv);
    fill_direct_kernel<<<EGRID, 256, 0, stream>>>(edata, row_ptr, dinv, csr8);

    // layer 1: aggb = A_hat @ x ; h = relu(aggb @ W1 + b1), bf16 out
    gather_kernel<<<AGRID, 256, 0, stream>>>(xb, row_ptr, csr8, dinv, aggb);
    gemm_mfma_kernel<<<GGRID, 256, 0, stream>>>(aggb, wsw1, b1, flagF, h, 1);

    // layer 2: aggb = A_hat @ h ; out = relu(aggb @ W2 + b2), dtype follows input
    gather_kernel<<<AGRID, 256, 0, stream>>>(h, row_ptr, csr8, dinv, aggb);
    gemm_mfma_kernel<<<GGRID, 256, 0, stream>>>(aggb, wsw2, b2, flagF, d_out, 2);
}